// Round 13
// baseline (54.440 us; speedup 1.0000x reference)
//
#include <hip/hip_runtime.h>
#include <math.h>

// Bit-exact float32 replication of the JAX-CPU reference chain.
#pragma clang fp contract(off)

#define BN 65536
#define SN 4
#define HH 128
#define WW 128

typedef float v4f __attribute__((ext_vector_type(4)));
typedef int v4i __attribute__((ext_vector_type(4)));
// Declared intrinsic (R7-validated): compiler tracks vmcnt precisely; OOB
// voffset lanes return 0, NO memory request.
__device__ v4f __llvm_buffer_load_v4f32(v4i rsrc, int voffset, int soffset,
                                        int aux) __asm("llvm.amdgcn.raw.buffer.load.v4f32");

// ---------- bit-exact prologue math (validated R1-R12) ----------
__device__ __forceinline__ void inv4(const float* P, float U[4][4]) {
#pragma clang fp contract(off)
    float a = P[10];
    float b = P[11];
    float ra = 1.0f / a;
    float l32 = P[14] * ra;
    float t = l32 * b;
    float u33 = 0.0f - t;
    float rf0 = 1.0f / P[0];
    float rf1 = 1.0f / P[5];
    float ru  = 1.0f / u33;
#pragma unroll
    for (int i = 0; i < 4; i++)
#pragma unroll
        for (int j = 0; j < 4; j++) U[i][j] = 0.0f;
    U[0][0] = rf0;
    U[1][1] = rf1;
    float x3c2 = (0.0f - l32) * ru;
    float y2c2 = fmaf(0.0f - b, x3c2, 1.0f);
    U[2][2] = y2c2 * ra;
    U[3][2] = x3c2;
    float x3c3 = ru;
    float y2c3 = 0.0f - (b * x3c3);
    U[2][3] = y2c3 * ra;
    U[3][3] = x3c3;
}

__device__ __forceinline__ void xform(const float M[4][4], float x, float y, float z,
                                      float& ox, float& oy, float& oz) {
#pragma clang fp contract(off)
    float o[4];
#pragma unroll
    for (int i = 0; i < 4; i++) {
        float acc = x * M[i][0];
        acc = acc + y * M[i][1];
        acc = acc + z * M[i][2];
        acc = acc + M[i][3];
        o[i] = acc;
    }
    ox = o[0] / o[3];
    oy = o[1] / o[3];
    oz = o[2] / o[3];
}

struct RS {
    float p0, p1, p2, d0, d1, d2;
    float y0, y1;          // RN(1/d0), RN(1/d1) — IEEE div, once per ray
    float fx, cy1;         // exact (cx+sx)/128 and 1-(cy+sy)/128
    float sxf, syf;        // sx/128, sy/128 (exact)
    float da, db, dc, hdz;
    int cx, cy, sx, sy, base, B, hoff, hk;
    bool still, testing, hit;
};

__device__ __forceinline__ void make_ray(RS& S, int r, const float* proj,
                                         const int* idxA, const int* xA, const int* yA,
                                         const float* dA, const float* dsA) {
#pragma clang fp contract(off)
    float P[4][4];
#pragma unroll
    for (int i = 0; i < 16; i++) ((float*)P)[i] = proj[i];
    float U[4][4];
    inv4(proj, U);
    int xi = xA[r], yi = yA[r];
    float t0 = ((float)xi + 0.5f) / 128.0f;
    float t1 = 1.0f - ((float)yi + 0.5f) / 128.0f;
    float ux = t0 * 2.0f - 1.0f;
    float uy = t1 * 2.0f - 1.0f;
    float ds = dsA[r] * 2.0f - 1.0f;
    float vx, vy, vz;
    xform(U, ux, uy, ds, vx, vy, vz);
    float ex = vx + dA[3 * r + 0] * 0.001f;
    float ey = vy + dA[3 * r + 1] * 0.001f;
    float ez = vz + dA[3 * r + 2] * 0.001f;
    float qx, qy, qz;
    xform(P, ex, ey, ez, qx, qy, qz);
    S.d0 = qx - ux;
    S.d1 = qy - uy;
    S.d2 = qz - ds;
    S.p0 = (ux + 1.0f) * 0.5f;
    S.p1 = (uy + 1.0f) * 0.5f;
    S.p2 = (ds + 1.0f) * 0.5f;
    S.sx = (S.d0 >= 0.0f) ? 1 : -1;
    S.sy = (S.d1 >= 0.0f) ? -1 : 1;
    S.cx = xi;
    S.cy = yi;
    // --- initial march (bit-identical to reference _march_next) ---
    {
        float nbx = (float)(S.cx + S.sx) / 128.0f;
        float nby = (float)(S.cy + S.sy) / 128.0f;
        float c1 = 1.0f - nby;
        float s0 = (nbx - S.p0) / S.d0;     // IEEE div (prologue only)
        float s1 = (c1 - S.p1) / S.d1;
        bool ty = s0 > s1;
        float t = ty ? s1 : s0;
        if (s1 != s1) t = s1;
        S.p0 = S.p0 + S.d0 * t;
        S.p1 = S.p1 + S.d1 * t;
        S.p2 = S.p2 + S.d2 * t;
        if (ty) S.cy += S.sy; else S.cx += S.sx;
    }
    S.y0 = 1.0f / S.d0;
    S.y1 = 1.0f / S.d1;
    S.fx  = (float)(S.cx + S.sx) / 128.0f;           // exact multiple of 1/128
    S.cy1 = 1.0f - (float)(S.cy + S.sy) / 128.0f;    // exact
    S.sxf = (float)S.sx * 0.0078125f;
    S.syf = (float)S.sy * 0.0078125f;
    S.da = dA[3 * r + 0]; S.db = dA[3 * r + 1]; S.dc = dA[3 * r + 2];
    S.base = idxA[r] * (HH * WW);
    S.B = 0; S.hoff = 0; S.hk = 0; S.hdz = 0.0f;
    S.still = true; S.testing = true; S.hit = false;
}

// Markstein correctly-rounded divide-by-invariant march (validated R4-R12).
#define MARCH { \
        float x0 = S.fx - S.p0; \
        float x1 = S.cy1 - S.p1; \
        float q0a = x0 * S.y0; \
        float rra = fmaf(-S.d0, q0a, x0); \
        float s0v = fmaf(rra, S.y0, q0a); \
        float q0b = x1 * S.y1; \
        float rrb = fmaf(-S.d1, q0b, x1); \
        float s1v = fmaf(rrb, S.y1, q0b); \
        bool ty = s0v > s1v; \
        float t = ty ? s1v : s0v; \
        t = (s1v != s1v) ? s1v : t; \
        float m0 = S.d0 * t; S.p0 = S.p0 + m0; \
        float m1 = S.d1 * t; S.p1 = S.p1 + m1; \
        float m2 = S.d2 * t; S.p2 = S.p2 + m2; \
        S.cx  += ty ? 0 : S.sx; \
        S.cy  += ty ? S.sy : 0; \
        S.fx  += ty ? 0.0f : S.sxf; \
        S.cy1 -= ty ? S.syf : 0.0f; }

// Phase-B-only march: cx/cy ints not needed (no loads, box check uses p only).
#define MARCH_NB { \
        float x0 = S.fx - S.p0; \
        float x1 = S.cy1 - S.p1; \
        float q0a = x0 * S.y0; \
        float rra = fmaf(-S.d0, q0a, x0); \
        float s0v = fmaf(rra, S.y0, q0a); \
        float q0b = x1 * S.y1; \
        float rrb = fmaf(-S.d1, q0b, x1); \
        float s1v = fmaf(rrb, S.y1, q0b); \
        bool ty = s0v > s1v; \
        float t = ty ? s1v : s0v; \
        t = (s1v != s1v) ? s1v : t; \
        float m0 = S.d0 * t; S.p0 = S.p0 + m0; \
        float m1 = S.d1 * t; S.p1 = S.p1 + m1; \
        float m2 = S.d2 * t; S.p2 = S.p2 + m2; \
        S.fx  += ty ? 0.0f : S.sxf; \
        S.cy1 -= ty ? S.syf : 0.0f; }

#define BOXCHK(inow) { \
        bool ib = (S.p0 >= 0.0f) && (S.p0 <= 1.0f) && \
                  (S.p1 >= 0.0f) && (S.p1 <= 1.0f) && \
                  (S.p2 > 0.0f) && (S.p2 < 1.0f); \
        S.still = S.still && ib; \
        S.B = S.still ? ((inow) + 1) : S.B; }

// Packed per-cell float4 table: (z, n0, n1, n2). 1 MB, L2-resident.
// Also resets ws[0] (same-stream ordering: completes before k_box).
__global__ __launch_bounds__(256) void k_pack(const float* __restrict__ depth,
                                              const float* __restrict__ normal,
                                              float4* __restrict__ tab, int* ws) {
    int t = blockIdx.x * 256 + threadIdx.x;
    if (t == 0) ws[0] = 0;
    int s = t >> 14;
    int c = t & 16383;
    float4 v;
    v.x = depth[t];
    v.y = normal[s * 3 * HH * WW + c];
    v.z = normal[s * 3 * HH * WW + HH * WW + c];
    v.w = normal[s * 3 * HH * WW + 2 * HH * WW + c];
    tab[t] = v;
}

__global__ void k_zero(int* ws) { ws[0] = 0; }

// B/N computation ONLY: pure VALU march + box prefix. No loads, no slots,
// ~22 VALU/state, tiny VGPR. Loop ends at the wave's last box exit.
__global__ __launch_bounds__(256, 1) void k_box(const int* idxA, const float* proj,
                                                const int* xA, const int* yA,
                                                const float* dA, const float* dsA,
                                                int* ws) {
#pragma clang fp contract(off)
    int r = blockIdx.x * 256 + threadIdx.x;
    RS S;
    make_ray(S, r, proj, idxA, xA, yA, dA, dsA);
    int i = 0;
    while (i < 4096 && __any(S.still)) {
#pragma unroll
        for (int u = 0; u < 8; ++u) {
            BOXCHK(i + u)
            MARCH_NB
        }
        i += 8;
    }
    int Bm = S.B;
    for (int o = 32; o; o >>= 1) {
        int v = __shfl_down(Bm, o, 64);
        Bm = Bm > v ? Bm : v;
    }
    if ((threadIdx.x & 63) == 0) atomicMax(ws, Bm);
}

// Hit search ONLY: 8-slot pipelined gathers (OOB-gated), dead-ray cutoff,
// NO box accounting. Loop ends when the wave's last tester retires.
template <bool PACKED>
__global__ __launch_bounds__(256, 1) void k_hit(const float* __restrict__ depth,
                                                const float* __restrict__ normal,
                                                const float4* __restrict__ tab,
                                                const int* idxA, const float* proj,
                                                const int* xA, const int* yA,
                                                const float* dA, const float* dsA,
                                                float* out) {
#pragma clang fp contract(off)
    int r = blockIdx.x * 256 + threadIdx.x;
    RS S;
    make_ray(S, r, proj, idxA, xA, yA, dA, dsA);
    const float* dep = depth + S.base;
    const float* nrm = normal + 3 * S.base;

    v4i rsrc;
    {
        unsigned long long p = (unsigned long long)(const void*)tab;
        rsrc.x = (int)(p & 0xFFFFFFFFull);
        rsrc.y = (int)(p >> 32);            // stride=0, no swizzle
        rsrc.z = SN * HH * WW * 16;         // num_records = bytes
        rsrc.w = 0x00020000;                // raw untyped dword access
    }

#define DECL_SLOT(u) \
    float z##u = 0.0f, a##u = 0.0f, b##u = 0.0f, c##u = 0.0f, q##u = 0.0f; \
    int o##u = 0; bool v##u = false;
    DECL_SLOT(0) DECL_SLOT(1) DECL_SLOT(2) DECL_SLOT(3)
    DECL_SLOT(4) DECL_SLOT(5) DECL_SLOT(6) DECL_SLOT(7)
#undef DECL_SLOT

#define CONSUME(u, kcons) { \
        float t0 = S.da * a##u; \
        float t1 = S.db * b##u; \
        float t2 = S.dc * c##u; \
        float dotv = (t0 + t1) + t2; \
        bool hc = v##u && (q##u >= z##u) && (dotv <= 0.0f) && !S.hit; \
        S.hit = S.hit || hc; \
        S.hoff = hc ? o##u : S.hoff; \
        S.hk   = hc ? (kcons) : S.hk; \
        float dzn = q##u - z##u; \
        S.hdz  = hc ? dzn : S.hdz; \
        v##u = false; }

#define STEP(u, inow) { \
        CONSUME(u, (inow) - 8) \
        { bool inpix = ((unsigned)S.cx < (unsigned)WW) && ((unsigned)S.cy < (unsigned)HH); \
          bool dead = (S.d2 <= 0.0f) && (S.p2 < 0.0f);   /* can never hit again */ \
          S.testing = S.testing && inpix && !S.hit && !dead; \
          int off = S.cy * WW + S.cx; \
          v##u = S.testing; o##u = off; q##u = S.p2; \
          if (PACKED) { \
              int voff = S.testing ? ((S.base + off) << 4) : 0x40000000; \
              v4f vv = __llvm_buffer_load_v4f32(rsrc, voff, 0, 0); \
              z##u = vv.x; a##u = vv.y; b##u = vv.z; c##u = vv.w; \
          } else if (S.testing) { \
              z##u = dep[off]; \
              a##u = nrm[off]; \
              b##u = nrm[HH * WW + off]; \
              c##u = nrm[2 * HH * WW + off]; \
          } } \
        MARCH }

    int i = 0;
    while (i < 4096) {
        STEP(0, i)     STEP(1, i + 1) STEP(2, i + 2) STEP(3, i + 3)
        STEP(4, i + 4) STEP(5, i + 5) STEP(6, i + 6) STEP(7, i + 7)
        i += 8;
        if (!__any(S.testing)) break;
    }
    // drain pending slots in state order (slot u holds state i-8+u)
    CONSUME(0, i - 8) CONSUME(1, i - 7) CONSUME(2, i - 6) CONSUME(3, i - 5)
    CONSUME(4, i - 4) CONSUME(5, i - 3) CONSUME(6, i - 2) CONSUME(7, i - 1)
#undef STEP
#undef CONSUME

    // record (hoff == (ry<<7)|rx since hits are always in-pixel)
    int pk = S.hit ? (S.hoff | (1 << 14)) : 0;
    out[2 * r]      = (float)pk;
    out[2 * r + 1]  = (float)S.hk;
    out[3 * BN + r] = S.hdz;
}

// Finalize: hit valid iff first-hit state index k < N (global trip count).
__global__ __launch_bounds__(256) void k_final(float* out, const int* ws) {
    int r = blockIdx.x * 256 + threadIdx.x;
    int N = ws[0];
    int pk = (int)out[2 * r];
    int k  = (int)out[2 * r + 1];
    float dzv = out[3 * BN + r];
    bool hit = (pk >> 14) & 1;
    bool ok = hit && (k < N);
    int rx = pk & 127, ry = (pk >> 7) & 127;
    out[2 * r]      = ok ? (float)rx : 0.0f;
    out[2 * r + 1]  = ok ? (float)ry : 0.0f;
    out[2 * BN + r] = ok ? 1.0f : 0.0f;
    out[3 * BN + r] = ok ? dzv : 0.0f;
}

extern "C" void kernel_launch(void* const* d_in, const int* in_sizes, int n_in,
                              void* d_out, int out_size, void* d_ws, size_t ws_size,
                              hipStream_t stream) {
    const float* depth = (const float*)d_in[0];
    const float* normal = (const float*)d_in[1];
    const int* indices = (const int*)d_in[2];
    const float* proj = (const float*)d_in[3];
    const int* x = (const int*)d_in[4];
    const int* y = (const int*)d_in[5];
    const float* d = (const float*)d_in[6];
    const float* ds = (const float*)d_in[7];
    float* out = (float*)d_out;
    int* ws = (int*)d_ws;

    const size_t tab_off = 64;
    const size_t need = tab_off + (size_t)SN * HH * WW * 16;
    float4* tab = (float4*)((char*)d_ws + tab_off);

    if (ws_size >= need) {   // host-uniform: graph-capture safe
        k_pack<<<(SN * HH * WW) / 256, 256, 0, stream>>>(depth, normal, tab, ws);
        k_hit<true><<<BN / 256, 256, 0, stream>>>(depth, normal, tab, indices,
                                                  proj, x, y, d, ds, out);
        k_box<<<BN / 256, 256, 0, stream>>>(indices, proj, x, y, d, ds, ws);
    } else {
        k_zero<<<1, 1, 0, stream>>>(ws);
        k_hit<false><<<BN / 256, 256, 0, stream>>>(depth, normal, tab, indices,
                                                   proj, x, y, d, ds, out);
        k_box<<<BN / 256, 256, 0, stream>>>(indices, proj, x, y, d, ds, ws);
    }
    k_final<<<BN / 256, 256, 0, stream>>>(out, ws);
}

// Round 14
// 42.711 us; speedup vs baseline: 1.2746x; 1.2746x over previous
//
#include <hip/hip_runtime.h>
#include <math.h>

// Bit-exact float32 replication of the JAX-CPU reference chain.
#pragma clang fp contract(off)

#define BN 65536
#define SN 4
#define HH 128
#define WW 128

typedef float v4f __attribute__((ext_vector_type(4)));
typedef int v4i __attribute__((ext_vector_type(4)));
// Declared intrinsic (R7-validated): compiler tracks vmcnt precisely; OOB
// voffset lanes return 0, NO memory request.
__device__ v4f __llvm_buffer_load_v4f32(v4i rsrc, int voffset, int soffset,
                                        int aux) __asm("llvm.amdgcn.raw.buffer.load.v4f32");

// ---------- bit-exact prologue math (validated R1-R13) ----------
__device__ __forceinline__ void inv4(const float* P, float U[4][4]) {
#pragma clang fp contract(off)
    float a = P[10];
    float b = P[11];
    float ra = 1.0f / a;
    float l32 = P[14] * ra;
    float t = l32 * b;
    float u33 = 0.0f - t;
    float rf0 = 1.0f / P[0];
    float rf1 = 1.0f / P[5];
    float ru  = 1.0f / u33;
#pragma unroll
    for (int i = 0; i < 4; i++)
#pragma unroll
        for (int j = 0; j < 4; j++) U[i][j] = 0.0f;
    U[0][0] = rf0;
    U[1][1] = rf1;
    float x3c2 = (0.0f - l32) * ru;
    float y2c2 = fmaf(0.0f - b, x3c2, 1.0f);
    U[2][2] = y2c2 * ra;
    U[3][2] = x3c2;
    float x3c3 = ru;
    float y2c3 = 0.0f - (b * x3c3);
    U[2][3] = y2c3 * ra;
    U[3][3] = x3c3;
}

__device__ __forceinline__ void xform(const float M[4][4], float x, float y, float z,
                                      float& ox, float& oy, float& oz) {
#pragma clang fp contract(off)
    float o[4];
#pragma unroll
    for (int i = 0; i < 4; i++) {
        float acc = x * M[i][0];
        acc = acc + y * M[i][1];
        acc = acc + z * M[i][2];
        acc = acc + M[i][3];
        o[i] = acc;
    }
    ox = o[0] / o[3];
    oy = o[1] / o[3];
    oz = o[2] / o[3];
}

struct RS {
    float p0, p1, p2, d0, d1, d2;
    float y0, y1;          // RN(1/d0), RN(1/d1) — IEEE div, once per ray
    float fx, cy1;         // exact (cx+sx)/128 and 1-(cy+sy)/128
    float sxf, syf;        // sx/128, sy/128 (exact)
    float da, db, dc, hdz;
    int cx, cy, sx, sy, base, B, hoff, hk;
    bool still, testing, hit;
};

__device__ __forceinline__ void make_ray(RS& S, int r, const float* proj,
                                         const int* idxA, const int* xA, const int* yA,
                                         const float* dA, const float* dsA) {
#pragma clang fp contract(off)
    float P[4][4];
#pragma unroll
    for (int i = 0; i < 16; i++) ((float*)P)[i] = proj[i];
    float U[4][4];
    inv4(proj, U);
    int xi = xA[r], yi = yA[r];
    float t0 = ((float)xi + 0.5f) / 128.0f;
    float t1 = 1.0f - ((float)yi + 0.5f) / 128.0f;
    float ux = t0 * 2.0f - 1.0f;
    float uy = t1 * 2.0f - 1.0f;
    float ds = dsA[r] * 2.0f - 1.0f;
    float vx, vy, vz;
    xform(U, ux, uy, ds, vx, vy, vz);
    float ex = vx + dA[3 * r + 0] * 0.001f;
    float ey = vy + dA[3 * r + 1] * 0.001f;
    float ez = vz + dA[3 * r + 2] * 0.001f;
    float qx, qy, qz;
    xform(P, ex, ey, ez, qx, qy, qz);
    S.d0 = qx - ux;
    S.d1 = qy - uy;
    S.d2 = qz - ds;
    S.p0 = (ux + 1.0f) * 0.5f;
    S.p1 = (uy + 1.0f) * 0.5f;
    S.p2 = (ds + 1.0f) * 0.5f;
    S.sx = (S.d0 >= 0.0f) ? 1 : -1;
    S.sy = (S.d1 >= 0.0f) ? -1 : 1;
    S.cx = xi;
    S.cy = yi;
    // --- initial march (bit-identical to reference _march_next) ---
    {
        float nbx = (float)(S.cx + S.sx) / 128.0f;
        float nby = (float)(S.cy + S.sy) / 128.0f;
        float c1 = 1.0f - nby;
        float s0 = (nbx - S.p0) / S.d0;     // IEEE div (prologue only)
        float s1 = (c1 - S.p1) / S.d1;
        bool ty = s0 > s1;
        float t = ty ? s1 : s0;
        if (s1 != s1) t = s1;
        S.p0 = S.p0 + S.d0 * t;
        S.p1 = S.p1 + S.d1 * t;
        S.p2 = S.p2 + S.d2 * t;
        if (ty) S.cy += S.sy; else S.cx += S.sx;
    }
    S.y0 = 1.0f / S.d0;
    S.y1 = 1.0f / S.d1;
    S.fx  = (float)(S.cx + S.sx) / 128.0f;           // exact multiple of 1/128
    S.cy1 = 1.0f - (float)(S.cy + S.sy) / 128.0f;    // exact
    S.sxf = (float)S.sx * 0.0078125f;
    S.syf = (float)S.sy * 0.0078125f;
    S.da = dA[3 * r + 0]; S.db = dA[3 * r + 1]; S.dc = dA[3 * r + 2];
    S.base = idxA[r] * (HH * WW);
    S.B = 0; S.hoff = 0; S.hk = 0; S.hdz = 0.0f;
    S.still = true; S.testing = true; S.hit = false;
}

// Markstein correctly-rounded divide-by-invariant march (validated R4-R13).
#define MARCH { \
        float x0 = S.fx - S.p0; \
        float x1 = S.cy1 - S.p1; \
        float q0a = x0 * S.y0; \
        float rra = fmaf(-S.d0, q0a, x0); \
        float s0v = fmaf(rra, S.y0, q0a); \
        float q0b = x1 * S.y1; \
        float rrb = fmaf(-S.d1, q0b, x1); \
        float s1v = fmaf(rrb, S.y1, q0b); \
        bool ty = s0v > s1v; \
        float t = ty ? s1v : s0v; \
        t = (s1v != s1v) ? s1v : t; \
        float m0 = S.d0 * t; S.p0 = S.p0 + m0; \
        float m1 = S.d1 * t; S.p1 = S.p1 + m1; \
        float m2 = S.d2 * t; S.p2 = S.p2 + m2; \
        S.cx  += ty ? 0 : S.sx; \
        S.cy  += ty ? S.sy : 0; \
        S.fx  += ty ? 0.0f : S.sxf; \
        S.cy1 -= ty ? S.syf : 0.0f; }

// Box prefix check; B is counted relative to shard base (exact merge later).
#define BOXCHK(inow, bse) { \
        bool ib = (S.p0 >= 0.0f) && (S.p0 <= 1.0f) && \
                  (S.p1 >= 0.0f) && (S.p1 <= 1.0f) && \
                  (S.p2 > 0.0f) && (S.p2 < 1.0f); \
        S.still = S.still && ib; \
        S.B = S.still ? ((inow) + 1 - (bse)) : S.B; }

#define CONSUME(u, kcons) { \
        float t0 = S.da * a##u; \
        float t1 = S.db * b##u; \
        float t2 = S.dc * c##u; \
        float dotv = (t0 + t1) + t2; \
        bool hc = v##u && (q##u >= z##u) && (dotv <= 0.0f) && !S.hit; \
        S.hit = S.hit || hc; \
        S.hoff = hc ? o##u : S.hoff; \
        S.hk   = hc ? (kcons) : S.hk; \
        float dzn = q##u - z##u; \
        S.hdz  = hc ? dzn : S.hdz; \
        v##u = false; }

// Heavy step: consume (lag 8), box-account, OOB-gated gather, march.
#define STEP(u, inow, bse) { \
        CONSUME(u, (inow) - 8) \
        BOXCHK(inow, bse) \
        { bool inpix = ((unsigned)S.cx < (unsigned)WW) && ((unsigned)S.cy < (unsigned)HH); \
          bool dead = (S.d2 <= 0.0f) && (S.p2 < 0.0f);   /* can never hit again */ \
          S.testing = S.testing && inpix && !S.hit && !dead; \
          int off = S.cy * WW + S.cx; \
          v##u = S.testing; o##u = off; q##u = S.p2; \
          int voff = S.testing ? ((S.base + off) << 4) : 0x40000000; \
          v4f vv = __llvm_buffer_load_v4f32(rsrc, voff, 0, 0); \
          z##u = vv.x; a##u = vv.y; b##u = vv.z; c##u = vv.w; } \
        MARCH }

#define DECL_SLOTS \
    float z0=0,a0=0,b0=0,c0=0,q0=0; int o0=0; bool v0=false; \
    float z1=0,a1=0,b1=0,c1=0,q1=0; int o1=0; bool v1=false; \
    float z2=0,a2=0,b2=0,c2=0,q2=0; int o2=0; bool v2=false; \
    float z3=0,a3=0,b3=0,c3=0,q3=0; int o3=0; bool v3=false; \
    float z4=0,a4=0,b4=0,c4=0,q4=0; int o4=0; bool v4=false; \
    float z5=0,a5=0,b5=0,c5=0,q5=0; int o5=0; bool v5=false; \
    float z6=0,a6=0,b6=0,c6=0,q6=0; int o6=0; bool v6=false; \
    float z7=0,a7=0,b7=0,c7=0,q7=0; int o7=0; bool v7=false;

// Packed per-cell float4 table: (z, n0, n1, n2). 1 MB, L2-resident.
// Also resets ws[0] (same-stream ordering: completes before march).
__global__ __launch_bounds__(256) void k_pack(const float* __restrict__ depth,
                                              const float* __restrict__ normal,
                                              float4* __restrict__ tab, int* ws) {
    int t = blockIdx.x * 256 + threadIdx.x;
    if (t == 0) ws[0] = 0;
    int s = t >> 14;
    int c = t & 16383;
    float4 v;
    v.x = depth[t];
    v.y = normal[s * 3 * HH * WW + c];
    v.z = normal[s * 3 * HH * WW + HH * WW + c];
    v.w = normal[s * 3 * HH * WW + 2 * HH * WW + c];
    tab[t] = v;
}

__global__ void k_zero(int* ws) { ws[0] = 0; }

// State-range-sharded march. Block = 128 rays x 2 shards (different waves).
// Shard A (tid<128): heavy-test states 0..127 (+ box prefix 0..127).
// Shard B: replay 0..127 with bare MARCH (bit-exact, ~50cy/state, no loads),
// then heavy-test 128..255 (+ local box count from 128). Hits have k<=255
// (in-pixel is a prefix of length <=256), and k<N <=> k<min(N,256) for
// k<=255, so 0..255 box coverage is exact for the filter. Merge in LDS:
// A-priority first hit (kA<128<=kB); B = (B_A==128) ? 128+localB : B_A.
__global__ __launch_bounds__(256, 1) void k_march_s(const float4* __restrict__ tab,
                                                    const int* idxA, const float* proj,
                                                    const int* xA, const int* yA,
                                                    const float* dA, const float* dsA,
                                                    float* out, int* ws) {
#pragma clang fp contract(off)
    __shared__ int smPk[128];
    __shared__ int smK[128];
    __shared__ float smDz[128];
    __shared__ int smLB[128];

    int tid = threadIdx.x;
    bool isB = tid >= 128;
    int r = blockIdx.x * 128 + (tid & 127);
    RS S;
    make_ray(S, r, proj, idxA, xA, yA, dA, dsA);

    v4i rsrc;
    {
        unsigned long long p = (unsigned long long)(const void*)tab;
        rsrc.x = (int)(p & 0xFFFFFFFFull);
        rsrc.y = (int)(p >> 32);            // stride=0, no swizzle
        rsrc.z = SN * HH * WW * 16;         // num_records = bytes
        rsrc.w = 0x00020000;                // raw untyped dword access
    }

    DECL_SLOTS

    if (!isB) {
        // ---- Shard A: heavy 0..127 ----
        int i = 0;
        while (i < 128 && __any(S.testing)) {
            STEP(0, i, 0)     STEP(1, i + 1, 0) STEP(2, i + 2, 0) STEP(3, i + 3, 0)
            STEP(4, i + 4, 0) STEP(5, i + 5, 0) STEP(6, i + 6, 0) STEP(7, i + 7, 0)
            i += 8;
        }
        CONSUME(0, i - 8) CONSUME(1, i - 7) CONSUME(2, i - 6) CONSUME(3, i - 5)
        CONSUME(4, i - 4) CONSUME(5, i - 3) CONSUME(6, i - 2) CONSUME(7, i - 1)
        // box continuation to state 127 (light)
        while (i < 128 && __any(S.still)) {
#pragma unroll
            for (int u = 0; u < 8; ++u) {
                BOXCHK(i + u, 0)
                MARCH
            }
            i += 8;
        }
    } else {
        // ---- Shard B: bit-exact light replay of states 0..127 ----
        for (int j = 0; j < 16; ++j) {
#pragma unroll
            for (int u = 0; u < 8; ++u) MARCH
        }
        // heavy 128..255 (testing init true; inpix/dead latches self-contained:
        // in-pixel and box exits are monotone, dead test is stateless)
        int i = 128;
        while (i < 256 && __any(S.testing)) {
            STEP(0, i, 128)     STEP(1, i + 1, 128) STEP(2, i + 2, 128) STEP(3, i + 3, 128)
            STEP(4, i + 4, 128) STEP(5, i + 5, 128) STEP(6, i + 6, 128) STEP(7, i + 7, 128)
            i += 8;
        }
        CONSUME(0, i - 8) CONSUME(1, i - 7) CONSUME(2, i - 6) CONSUME(3, i - 5)
        CONSUME(4, i - 4) CONSUME(5, i - 3) CONSUME(6, i - 2) CONSUME(7, i - 1)
        while (i < 256 && __any(S.still)) {
#pragma unroll
            for (int u = 0; u < 8; ++u) {
                BOXCHK(i + u, 128)
                MARCH
            }
            i += 8;
        }
        int idx = tid - 128;
        smPk[idx] = S.hit ? (S.hoff | (1 << 14)) : 0;
        smK[idx]  = S.hk;
        smDz[idx] = S.hdz;
        smLB[idx] = S.B;
    }
    __syncthreads();
    if (!isB) {
        int idx = tid;
        int pkB = smPk[idx];
        bool hA = S.hit;
        bool hB = (pkB >> 14) & 1;
        int pk  = hA ? (S.hoff | (1 << 14)) : (hB ? pkB : 0);
        int k   = hA ? S.hk : (hB ? smK[idx] : 0);
        float dz = hA ? S.hdz : (hB ? smDz[idx] : 0.0f);
        int Bm = (S.B == 128) ? (128 + smLB[idx]) : S.B;   // exact min(B,256)
        out[2 * r]      = (float)pk;
        out[2 * r + 1]  = (float)k;
        out[3 * BN + r] = dz;
        for (int o = 32; o; o >>= 1) {
            int v = __shfl_down(Bm, o, 64);
            Bm = Bm > v ? Bm : v;
        }
        if ((tid & 63) == 0) atomicMax(ws, Bm);
    }
}

// Fallback (ws too small): R12 merged mono kernel, unpacked loads.
__global__ __launch_bounds__(256, 1) void k_march_mono(const float* __restrict__ depth,
                                                       const float* __restrict__ normal,
                                                       const int* idxA, const float* proj,
                                                       const int* xA, const int* yA,
                                                       const float* dA, const float* dsA,
                                                       float* out, int* ws) {
#pragma clang fp contract(off)
    int r = blockIdx.x * 256 + threadIdx.x;
    RS S;
    make_ray(S, r, proj, idxA, xA, yA, dA, dsA);
    const float* dep = depth + S.base;
    const float* nrm = normal + 3 * S.base;
    DECL_SLOTS
#define STEPU(u, inow) { \
        CONSUME(u, (inow) - 8) \
        BOXCHK(inow, 0) \
        { bool inpix = ((unsigned)S.cx < (unsigned)WW) && ((unsigned)S.cy < (unsigned)HH); \
          bool dead = (S.d2 <= 0.0f) && (S.p2 < 0.0f); \
          S.testing = S.testing && inpix && !S.hit && !dead; \
          int off = S.cy * WW + S.cx; \
          v##u = S.testing; o##u = off; q##u = S.p2; \
          if (S.testing) { \
              z##u = dep[off]; \
              a##u = nrm[off]; \
              b##u = nrm[HH * WW + off]; \
              c##u = nrm[2 * HH * WW + off]; \
          } } \
        MARCH }
    int i = 0;
    while (i < 4096) {
        STEPU(0, i)     STEPU(1, i + 1) STEPU(2, i + 2) STEPU(3, i + 3)
        STEPU(4, i + 4) STEPU(5, i + 5) STEPU(6, i + 6) STEPU(7, i + 7)
        i += 8;
        if (!__any(S.testing)) break;
    }
    CONSUME(0, i - 8) CONSUME(1, i - 7) CONSUME(2, i - 6) CONSUME(3, i - 5)
    CONSUME(4, i - 4) CONSUME(5, i - 3) CONSUME(6, i - 2) CONSUME(7, i - 1)
    while (i < 4096 && __any(S.still)) {
#pragma unroll
        for (int u = 0; u < 8; ++u) {
            BOXCHK(i + u, 0)
            MARCH
        }
        i += 8;
    }
#undef STEPU
    int pk = S.hit ? (S.hoff | (1 << 14)) : 0;
    out[2 * r]      = (float)pk;
    out[2 * r + 1]  = (float)S.hk;
    out[3 * BN + r] = S.hdz;
    int Bm = S.B;
    for (int o = 32; o; o >>= 1) {
        int v = __shfl_down(Bm, o, 64);
        Bm = Bm > v ? Bm : v;
    }
    if ((threadIdx.x & 63) == 0) atomicMax(ws, Bm);
}

// Finalize: hit valid iff first-hit state index k < N (global trip count).
__global__ __launch_bounds__(256) void k_final(float* out, const int* ws) {
    int r = blockIdx.x * 256 + threadIdx.x;
    int N = ws[0];
    int pk = (int)out[2 * r];
    int k  = (int)out[2 * r + 1];
    float dzv = out[3 * BN + r];
    bool hit = (pk >> 14) & 1;
    bool ok = hit && (k < N);
    int rx = pk & 127, ry = (pk >> 7) & 127;
    out[2 * r]      = ok ? (float)rx : 0.0f;
    out[2 * r + 1]  = ok ? (float)ry : 0.0f;
    out[2 * BN + r] = ok ? 1.0f : 0.0f;
    out[3 * BN + r] = ok ? dzv : 0.0f;
}

extern "C" void kernel_launch(void* const* d_in, const int* in_sizes, int n_in,
                              void* d_out, int out_size, void* d_ws, size_t ws_size,
                              hipStream_t stream) {
    const float* depth = (const float*)d_in[0];
    const float* normal = (const float*)d_in[1];
    const int* indices = (const int*)d_in[2];
    const float* proj = (const float*)d_in[3];
    const int* x = (const int*)d_in[4];
    const int* y = (const int*)d_in[5];
    const float* d = (const float*)d_in[6];
    const float* ds = (const float*)d_in[7];
    float* out = (float*)d_out;
    int* ws = (int*)d_ws;

    const size_t tab_off = 64;
    const size_t need = tab_off + (size_t)SN * HH * WW * 16;
    float4* tab = (float4*)((char*)d_ws + tab_off);

    if (ws_size >= need) {   // host-uniform: graph-capture safe
        k_pack<<<(SN * HH * WW) / 256, 256, 0, stream>>>(depth, normal, tab, ws);
        k_march_s<<<BN / 128, 256, 0, stream>>>(tab, indices, proj, x, y, d, ds, out, ws);
    } else {
        k_zero<<<1, 1, 0, stream>>>(ws);
        k_march_mono<<<BN / 256, 256, 0, stream>>>(depth, normal, indices, proj,
                                                   x, y, d, ds, out, ws);
    }
    k_final<<<BN / 256, 256, 0, stream>>>(out, ws);
}